// Round 1
// baseline (72.634 us; speedup 1.0000x reference)
//
#include <hip/hip_runtime.h>
#include <hip/hip_bf16.h>

// ChamferDistanceMatrixL2: B=32, G=64, N=32, C=3.
// out[b][g1][g2] = mean_n min_m d(n,m) + mean_m min_n d(n,m),
// d(n,m) = |xyz1[b,g1,n] - xyz2[b,g2,m]|^2 = s1 + s2 - 2*dot.
//
// One thread per output element. lane = g2, wave = g1 (so p1 loads are
// wave-uniform -> one L1 line request), g2's 32 points register-resident
// as (qx,qy,qz,s2) with q = -2*p2 so each distance is 3 FMA + 1 add + 2 min.
// No LDS, no shuffles, no barriers. ~190 VGPR -> 2 waves/SIMD; grid of
// 2048 waves fills all 1024 SIMDs x2 in a single residency round.

__global__ __launch_bounds__(256, 2)
void chamfer_dist_kernel(const float* __restrict__ xyz1,
                         const float* __restrict__ xyz2,
                         float* __restrict__ out) {
    const int b    = blockIdx.x >> 4;                               // 0..31
    const int g1   = ((blockIdx.x & 15) << 2) | (threadIdx.x >> 6); // 0..63
    const int g2   = threadIdx.x & 63;                              // 0..63

    // ---- register-cache group g2: q = -2*p2, s2 = |p2|^2 ----
    const float* __restrict__ p2 = xyz2 + (size_t)(b * 64 + g2) * 96;
    float qx[32], qy[32], qz[32], s2[32];
#pragma unroll
    for (int m = 0; m < 32; ++m) {
        const float x = p2[3 * m + 0];
        const float y = p2[3 * m + 1];
        const float z = p2[3 * m + 2];
        s2[m] = fmaf(x, x, fmaf(y, y, z * z));
        qx[m] = -2.0f * x;
        qy[m] = -2.0f * y;
        qz[m] = -2.0f * z;
    }

    float colmin[32];
#pragma unroll
    for (int m = 0; m < 32; ++m) colmin[m] = 3.0e38f;

    const float* __restrict__ p1 = xyz1 + (size_t)(b * 64 + g1) * 96;
    float sum1 = 0.0f;

#pragma unroll 4
    for (int n = 0; n < 32; ++n) {
        const float x1 = p1[3 * n + 0];   // wave-uniform address
        const float y1 = p1[3 * n + 1];
        const float z1 = p1[3 * n + 2];
        const float s1 = fmaf(x1, x1, fmaf(y1, y1, z1 * z1));
        float rmin = 3.0e38f;
#pragma unroll
        for (int m = 0; m < 32; ++m) {
            const float u = s1 + s2[m];
            const float t = fmaf(x1, qx[m], fmaf(y1, qy[m], fmaf(z1, qz[m], u)));
            rmin      = fminf(rmin, t);
            colmin[m] = fminf(colmin[m], t);
        }
        sum1 += rmin;
    }

    float sum2 = 0.0f;
#pragma unroll
    for (int m = 0; m < 32; ++m) sum2 += colmin[m];

    out[(size_t)(b * 64 + g1) * 64 + g2] = (sum1 + sum2) * (1.0f / 32.0f);
}

extern "C" void kernel_launch(void* const* d_in, const int* in_sizes, int n_in,
                              void* d_out, int out_size, void* d_ws, size_t ws_size,
                              hipStream_t stream) {
    const float* xyz1 = (const float*)d_in[0];
    const float* xyz2 = (const float*)d_in[1];
    float* out = (float*)d_out;

    dim3 grid(512);   // 32 b * 16 g1-quads
    dim3 block(256);  // 4 waves (g1) * 64 lanes (g2)
    chamfer_dist_kernel<<<grid, block, 0, stream>>>(xyz1, xyz2, out);
}